// Round 1
// baseline (29306.107 us; speedup 1.0000x reference)
//
#include <hip/hip_runtime.h>
#include <math.h>

// Problem constants (match reference)
constexpr int B_   = 64;
constexpr int T_   = 200;
constexpr int L_IN = 100;
constexpr int S_   = 8;
constexpr int XC_  = 16;
constexpr int H_   = 256;
constexpr int W_   = 128;
constexpr int O_   = 8;
constexpr int GR_  = 3 * H_;      // 768
constexpr int HXC  = H_ * XC_;    // 4096

#define NT 256

// Workspace layout (floats): transposed (k-major) weights
constexpr size_t OFF_WIHT = 0;                           // [24][768]
constexpr size_t OFF_WHHT = OFF_WIHT + 24ull * GR_;      // [256][768]
constexpr size_t OFF_W0T  = OFF_WHHT + (size_t)H_ * GR_; // [256][128]
constexpr size_t OFF_W1T  = OFF_W0T + (size_t)H_ * W_;   // [128][128]
constexpr size_t OFF_W2T  = OFF_W1T + (size_t)W_ * W_;   // [128][4096]
constexpr size_t WS_FLOATS = OFF_W2T + (size_t)W_ * HXC; // 788480 floats ~ 3.01 MB

// Transpose: in is R x K row-major; out[k*R + j] = in[j*K + k]
__global__ void transpose_kernel(const float* __restrict__ in, float* __restrict__ out,
                                 int R, int K) {
    int o = blockIdx.x * blockDim.x + threadIdx.x;
    if (o < R * K) {
        int k = o / R;
        int j = o - k * R;
        out[o] = in[j * K + k];
    }
}

__device__ __forceinline__ float softplus_f(float x) {
    return fmaxf(x, 0.f) + log1pf(expf(-fabsf(x)));
}
__device__ __forceinline__ float sigmoid_f(float x) {
    return 1.f / (1.f + expf(-x));
}

template <bool TR>
__global__ __launch_bounds__(NT) void gru_cde_kernel(
    const float* __restrict__ y_past,   // [B][L_IN][S]
    const float* __restrict__ tvals,    // [T]
    const float* __restrict__ cx,       // [B][T][XC-1]
    const float* __restrict__ wih,      // TR ? [24][768] : [768][24]
    const float* __restrict__ whh,      // TR ? [256][768] : [768][256]
    const float* __restrict__ gru_b,    // [768]
    const float* __restrict__ gru_bn,   // [256]
    const float* __restrict__ w0,       // TR ? [256][128] : [128][256]
    const float* __restrict__ b0,       // [128]
    const float* __restrict__ w1,       // [128][128] (TR: k-major)
    const float* __restrict__ b1,       // [128]
    const float* __restrict__ w2,       // TR ? [128][4096] : [4096][128]
    const float* __restrict__ b2,       // [4096]
    const float* __restrict__ ro_w,     // [8][256]
    const float* __restrict__ ro_b,     // [8]
    float* __restrict__ out)            // [B][100][8]
{
    const int b   = blockIdx.x;
    const int tid = threadIdx.x;

    __shared__ float z[H_];        // hidden state / ODE state
    __shared__ float zs[H_];       // stage input
    __shared__ float kb[6][H_];    // dopri5 k vectors
    __shared__ float a0s[W_];
    __shared__ float a1s[W_];
    __shared__ float xb[S_ + XC_]; // 24
    __shared__ float dxs[XC_];

    // ---------------- Encoder: 100 GRU steps ----------------
    z[tid] = 0.f;   // NT == H_ == 256
    __syncthreads();

    for (int step = 0; step < L_IN; ++step) {
        if (tid < S_ + XC_) {
            float v;
            if (tid < S_)            v = y_past[(b * L_IN + step) * S_ + tid];
            else if (tid < S_ + XC_ - 1) v = cx[(b * T_ + step) * (XC_ - 1) + (tid - S_)];
            else                     v = tvals[step];
            xb[tid] = v;
        }
        __syncthreads();

        // thread tid owns gate rows tid (r), tid+256 (z), tid+512 (n)
        float gr = gru_b[tid];
        float gz = gru_b[tid + H_];
        float ia = gru_b[tid + 2 * H_];
        float hn = 0.f;

        #pragma unroll 4
        for (int k = 0; k < S_ + XC_; ++k) {
            float xv = xb[k];
            if constexpr (TR) {
                gr += wih[k * GR_ + tid] * xv;
                gz += wih[k * GR_ + tid + H_] * xv;
                ia += wih[k * GR_ + tid + 2 * H_] * xv;
            } else {
                gr += wih[tid * (S_ + XC_) + k] * xv;
                gz += wih[(tid + H_) * (S_ + XC_) + k] * xv;
                ia += wih[(tid + 2 * H_) * (S_ + XC_) + k] * xv;
            }
        }
        #pragma unroll 4
        for (int k = 0; k < H_; ++k) {
            float hv = z[k];
            if constexpr (TR) {
                gr += whh[k * GR_ + tid] * hv;
                gz += whh[k * GR_ + tid + H_] * hv;
                hn += whh[k * GR_ + tid + 2 * H_] * hv;
            } else {
                gr += whh[tid * H_ + k] * hv;
                gz += whh[(tid + H_) * H_ + k] * hv;
                hn += whh[(tid + 2 * H_) * H_ + k] * hv;
            }
        }

        float r = sigmoid_f(gr);
        float u = sigmoid_f(gz);
        float n = tanhf(ia + r * (hn + gru_bn[tid]));
        float hold = z[tid];
        float hnew = n + u * (hold - n);
        __syncthreads();
        z[tid] = hnew;
        __syncthreads();
    }

    // readout helper: out[b][idx][:] = ro_w @ z + ro_b
    auto readout = [&](int idx) {
        if (tid < O_) {
            float s = ro_b[tid];
            #pragma unroll 8
            for (int k = 0; k < H_; ++k) s += ro_w[tid * H_ + k] * z[k];
            out[(b * L_IN + idx) * O_ + tid] = s;
        }
    };

    readout(0);   // ys[0] = z0

    // vf: kb[s] = vf(zin, dxdt)
    auto vf = [&](const float* zin, int s) {
        // a0 = softplus(W0 @ zin + b0)
        if (tid < W_) {
            float acc = b0[tid];
            #pragma unroll 8
            for (int k = 0; k < H_; ++k) {
                float wv = TR ? w0[k * W_ + tid] : w0[tid * H_ + k];
                acc += wv * zin[k];
            }
            a0s[tid] = softplus_f(acc);
        }
        __syncthreads();
        // a1 = softplus(W1 @ a0 + b1)
        if (tid < W_) {
            float acc = b1[tid];
            #pragma unroll 8
            for (int k = 0; k < W_; ++k) {
                float wv = TR ? w1[k * W_ + tid] : w1[tid * W_ + k];
                acc += wv * a0s[k];
            }
            a1s[tid] = softplus_f(acc);
        }
        __syncthreads();
        // f = tanh(W2 @ a1 + b2) reshaped [256][16]; k = f @ dxdt
        #pragma unroll
        for (int pass = 0; pass < HXC / (NT * 4); ++pass) {   // 4 passes
            int jj = (pass * NT + tid) * 4;                   // 4 consecutive rows
            float4 acc = make_float4(0.f, 0.f, 0.f, 0.f);
            if constexpr (TR) {
                const float4* w24 = reinterpret_cast<const float4*>(w2);
                int jt = jj >> 2;
                #pragma unroll 8
                for (int k = 0; k < W_; ++k) {
                    float4 wv = w24[k * (HXC / 4) + jt];
                    float av = a1s[k];
                    acc.x += wv.x * av; acc.y += wv.y * av;
                    acc.z += wv.z * av; acc.w += wv.w * av;
                }
            } else {
                #pragma unroll 4
                for (int k = 0; k < W_; ++k) {
                    float av = a1s[k];
                    acc.x += w2[(jj + 0) * W_ + k] * av;
                    acc.y += w2[(jj + 1) * W_ + k] * av;
                    acc.z += w2[(jj + 2) * W_ + k] * av;
                    acc.w += w2[(jj + 3) * W_ + k] * av;
                }
            }
            const float4 bb = reinterpret_cast<const float4*>(b2)[jj >> 2];
            int c0 = jj & 15;
            float p = tanhf(acc.x + bb.x) * dxs[c0]
                    + tanhf(acc.y + bb.y) * dxs[c0 + 1]
                    + tanhf(acc.z + bb.z) * dxs[c0 + 2]
                    + tanhf(acc.w + bb.w) * dxs[c0 + 3];
            // rows jj..jj+3 share z-row i = jj>>4 with threads tid^1, tid^2
            p += __shfl_xor(p, 1);
            p += __shfl_xor(p, 2);
            if ((tid & 3) == 0) kb[s][pass * 64 + (tid >> 2)] = p;
        }
        __syncthreads();
    };

    // ---------------- ODE: 99 intervals x 2 dopri5 substeps ----------------
    for (int i = 0; i < T_ - L_IN - 1; ++i) {   // 99 intervals
        float dt = tvals[L_IN + i + 1] - tvals[L_IN + i];
        if (tid < XC_) {
            float xa, xbv;
            if (tid < XC_ - 1) {
                xa  = cx[(b * T_ + L_IN + i) * (XC_ - 1) + tid];
                xbv = cx[(b * T_ + L_IN + i + 1) * (XC_ - 1) + tid];
            } else {
                xa  = tvals[L_IN + i];
                xbv = tvals[L_IN + i + 1];
            }
            dxs[tid] = (xbv - xa) / dt;
        }
        float hh = dt * 0.5f;   // N_SUB = 2
        __syncthreads();

        for (int sub = 0; sub < 2; ++sub) {
            // stage 1
            vf(z, 0);
            // stage 2
            zs[tid] = z[tid] + hh * (0.2f * kb[0][tid]);
            __syncthreads();
            vf(zs, 1);
            // stage 3
            zs[tid] = z[tid] + hh * (0.075f * kb[0][tid] + 0.225f * kb[1][tid]);
            __syncthreads();
            vf(zs, 2);
            // stage 4
            zs[tid] = z[tid] + hh * ((44.f / 45.f) * kb[0][tid]
                                   - (56.f / 15.f) * kb[1][tid]
                                   + (32.f / 9.f) * kb[2][tid]);
            __syncthreads();
            vf(zs, 3);
            // stage 5
            zs[tid] = z[tid] + hh * ((19372.f / 6561.f) * kb[0][tid]
                                   - (25360.f / 2187.f) * kb[1][tid]
                                   + (64448.f / 6561.f) * kb[2][tid]
                                   - (212.f / 729.f) * kb[3][tid]);
            __syncthreads();
            vf(zs, 4);
            // stage 6
            zs[tid] = z[tid] + hh * ((9017.f / 3168.f) * kb[0][tid]
                                   - (355.f / 33.f) * kb[1][tid]
                                   + (46732.f / 5247.f) * kb[2][tid]
                                   + (49.f / 176.f) * kb[3][tid]
                                   - (5103.f / 18656.f) * kb[4][tid]);
            __syncthreads();
            vf(zs, 5);
            // combine
            float znew = z[tid] + hh * ((35.f / 384.f) * kb[0][tid]
                                      + (500.f / 1113.f) * kb[2][tid]
                                      + (125.f / 192.f) * kb[3][tid]
                                      - (2187.f / 6784.f) * kb[4][tid]
                                      + (11.f / 84.f) * kb[5][tid]);
            __syncthreads();
            z[tid] = znew;
            __syncthreads();
        }
        readout(i + 1);
    }
}

extern "C" void kernel_launch(void* const* d_in, const int* in_sizes, int n_in,
                              void* d_out, int out_size, void* d_ws, size_t ws_size,
                              hipStream_t stream) {
    const float* y_past = (const float*)d_in[0];
    const float* tvals  = (const float*)d_in[1];
    const float* cx     = (const float*)d_in[2];
    const float* wih    = (const float*)d_in[3];
    const float* whh    = (const float*)d_in[4];
    const float* gb     = (const float*)d_in[5];
    const float* gbn    = (const float*)d_in[6];
    const float* w0     = (const float*)d_in[7];
    const float* b0     = (const float*)d_in[8];
    const float* w1     = (const float*)d_in[9];
    const float* b1     = (const float*)d_in[10];
    const float* w2     = (const float*)d_in[11];
    const float* b2     = (const float*)d_in[12];
    const float* ro_w   = (const float*)d_in[13];
    const float* ro_b   = (const float*)d_in[14];
    float* out = (float*)d_out;

    bool tr = ws_size >= WS_FLOATS * sizeof(float);
    if (tr) {
        float* ws = (float*)d_ws;
        auto launchT = [&](const float* in, float* o, int R, int K) {
            int n = R * K;
            transpose_kernel<<<(n + 255) / 256, 256, 0, stream>>>(in, o, R, K);
        };
        launchT(wih, ws + OFF_WIHT, GR_, S_ + XC_);
        launchT(whh, ws + OFF_WHHT, GR_, H_);
        launchT(w0,  ws + OFF_W0T,  W_, H_);
        launchT(w1,  ws + OFF_W1T,  W_, W_);
        launchT(w2,  ws + OFF_W2T,  HXC, W_);
        gru_cde_kernel<true><<<B_, NT, 0, stream>>>(
            y_past, tvals, cx,
            ws + OFF_WIHT, ws + OFF_WHHT, gb, gbn,
            ws + OFF_W0T, b0, ws + OFF_W1T, b1, ws + OFF_W2T, b2,
            ro_w, ro_b, out);
    } else {
        gru_cde_kernel<false><<<B_, NT, 0, stream>>>(
            y_past, tvals, cx,
            wih, whh, gb, gbn,
            w0, b0, w1, b1, w2, b2,
            ro_w, ro_b, out);
    }
}

// Round 2
// 22819.986 us; speedup vs baseline: 1.2842x; 1.2842x over previous
//
#include <hip/hip_runtime.h>
#include <math.h>

// Problem constants (match reference)
constexpr int B_   = 64;
constexpr int T_   = 200;
constexpr int L_IN = 100;
constexpr int S_   = 8;
constexpr int XC_  = 16;
constexpr int H_   = 256;
constexpr int W_   = 128;
constexpr int O_   = 8;
constexpr int GR_  = 3 * H_;      // 768
constexpr int HXC  = H_ * XC_;    // 4096

#define NT 1024

// Workspace layout (floats): transposed (k-major) weights
constexpr size_t OFF_WIHT = 0;                           // [24][768]
constexpr size_t OFF_WHHT = OFF_WIHT + 24ull * GR_;      // [256][768]
constexpr size_t OFF_W0T  = OFF_WHHT + (size_t)H_ * GR_; // [256][128]
constexpr size_t OFF_W1T  = OFF_W0T + (size_t)H_ * W_;   // [128][128]
constexpr size_t OFF_W2T  = OFF_W1T + (size_t)W_ * W_;   // [128][4096]
constexpr size_t WS_FLOATS = OFF_W2T + (size_t)W_ * HXC; // ~3.01 MB

// Transpose: in is R x K row-major; out[k*R + j] = in[j*K + k]
__global__ void transpose_kernel(const float* __restrict__ in, float* __restrict__ out,
                                 int R, int K) {
    int o = blockIdx.x * blockDim.x + threadIdx.x;
    if (o < R * K) {
        int k = o / R;
        int j = o - k * R;
        out[o] = in[j * K + k];
    }
}

__device__ __forceinline__ float softplus_f(float x) {
    return fmaxf(x, 0.f) + log1pf(expf(-fabsf(x)));
}
__device__ __forceinline__ float sigmoid_f(float x) {
    return 1.f / (1.f + expf(-x));
}

template <bool TR>
__global__ __launch_bounds__(NT) void gru_cde_kernel(
    const float* __restrict__ y_past,   // [B][L_IN][S]
    const float* __restrict__ tvals,    // [T]
    const float* __restrict__ cx,       // [B][T][XC-1]
    const float* __restrict__ wih,      // TR ? [24][768] : [768][24]
    const float* __restrict__ whh,      // TR ? [256][768] : [768][256]
    const float* __restrict__ gru_b,    // [768]
    const float* __restrict__ gru_bn,   // [256]
    const float* __restrict__ w0,       // TR ? [256][128] : [128][256]
    const float* __restrict__ b0,       // [128]
    const float* __restrict__ w1,       // [128][128] (TR: k-major)
    const float* __restrict__ b1,       // [128]
    const float* __restrict__ w2,       // TR ? [128][4096] : [4096][128]
    const float* __restrict__ b2,       // [4096]
    const float* __restrict__ ro_w,     // [8][256]
    const float* __restrict__ ro_b,     // [8]
    float* __restrict__ out)            // [B][100][8]
{
    const int b   = blockIdx.x;
    const int tid = threadIdx.x;

    __shared__ __align__(16) float z[H_];   // ODE / hidden state
    __shared__ float zs[H_];                // stage input
    __shared__ float kb[6][H_];             // dopri5 k vectors
    __shared__ float a0s[W_];
    __shared__ float a1s[W_];
    __shared__ float red[8][W_];            // split-K partials
    __shared__ float gsum[GR_];             // GRU gate pre-activations
    __shared__ float gaux[H_];              // GRU hn part
    __shared__ float xb[S_ + XC_];          // 24
    __shared__ float dxs[XC_];

    // per-thread constants cached in registers
    const float gb_t = (tid < GR_) ? gru_b[tid] : 0.f;
    const float bn_t = (tid < H_) ? gru_bn[tid] : 0.f;
    // b2 rows for W2 stage: thread owns rows 4*tid .. 4*tid+3 (constant all vf calls)
    const float4 bb = reinterpret_cast<const float4*>(b2)[tid];

    if (tid < H_) z[tid] = 0.f;
    __syncthreads();

    // ---------------- Encoder: 100 GRU steps ----------------
    for (int step = 0; step < L_IN; ++step) {
        if (tid < S_ + XC_) {
            float v;
            if (tid < S_)                v = y_past[(b * L_IN + step) * S_ + tid];
            else if (tid < S_ + XC_ - 1) v = cx[(b * T_ + step) * (XC_ - 1) + (tid - S_)];
            else                         v = tvals[step];
            xb[tid] = v;
        }
        __syncthreads();

        if (tid < GR_) {        // one gate-row per thread
            float ig = gb_t;
            #pragma unroll
            for (int k = 0; k < S_ + XC_; ++k) {
                float wv = TR ? wih[k * GR_ + tid] : wih[tid * (S_ + XC_) + k];
                ig += wv * xb[k];
            }
            float hg = 0.f;
            #pragma unroll 8
            for (int k = 0; k < H_; ++k) {
                float wv = TR ? whh[k * GR_ + tid] : whh[tid * H_ + k];
                hg += wv * z[k];
            }
            if (tid < 2 * H_) gsum[tid] = ig + hg;          // r, z gates: full sum
            else { gsum[tid] = ig; gaux[tid - 2 * H_] = hg; } // n gate: keep split
        }
        __syncthreads();

        if (tid < H_) {
            float r = sigmoid_f(gsum[tid]);
            float u = sigmoid_f(gsum[tid + H_]);
            float n = tanhf(gsum[tid + 2 * H_] + r * (gaux[tid] + bn_t));
            z[tid] = n + u * (z[tid] - n);
        }
        __syncthreads();
    }

    // readout: out[b][idx][:] = ro_w @ z + ro_b ; one wave per output row
    auto readout = [&](int idx) {
        if (tid < 8 * 64) {
            int o  = tid >> 6;           // output row, one wave each
            int kk = tid & 63;           // float4 chunk of z
            float4 wv = reinterpret_cast<const float4*>(ro_w)[o * 64 + kk];
            float4 zv = *reinterpret_cast<const float4*>(&z[kk * 4]);
            float p = wv.x * zv.x + wv.y * zv.y + wv.z * zv.z + wv.w * zv.w;
            p += __shfl_xor(p, 1);
            p += __shfl_xor(p, 2);
            p += __shfl_xor(p, 4);
            p += __shfl_xor(p, 8);
            p += __shfl_xor(p, 16);
            p += __shfl_xor(p, 32);
            if (kk == 0) out[(b * L_IN + idx) * O_ + o] = p + ro_b[o];
        }
    };

    readout(0);   // ys[0] = z0

    const float4* __restrict__ w24 = reinterpret_cast<const float4*>(w2);

    // vf: kb[s] = vf(zin, dxdt)
    auto vf = [&](const float* zin, int s) {
        const int g = tid >> 7;      // 0..7 split-K group
        const int r = tid & 127;     // output row
        // a0 = softplus(W0 @ zin + b0), 8-way split-K over 256
        {
            float acc = 0.f;
            const int k0 = g * 32;
            #pragma unroll 8
            for (int k = k0; k < k0 + 32; ++k) {
                float wv = TR ? w0[k * W_ + r] : w0[r * H_ + k];
                acc += wv * zin[k];
            }
            red[g][r] = acc;
        }
        __syncthreads();
        if (tid < W_) {
            float sa = b0[tid];
            #pragma unroll
            for (int gg = 0; gg < 8; ++gg) sa += red[gg][tid];
            a0s[tid] = softplus_f(sa);
        }
        __syncthreads();
        // a1 = softplus(W1 @ a0 + b1), 8-way split-K over 128
        {
            float acc = 0.f;
            const int k0 = g * 16;
            #pragma unroll
            for (int k = k0; k < k0 + 16; ++k) {
                float wv = TR ? w1[k * W_ + r] : w1[r * W_ + k];
                acc += wv * a0s[k];
            }
            red[g][r] = acc;
        }
        __syncthreads();
        if (tid < W_) {
            float sa = b1[tid];
            #pragma unroll
            for (int gg = 0; gg < 8; ++gg) sa += red[gg][tid];
            a1s[tid] = softplus_f(sa);
        }
        __syncthreads();
        // f = tanh(W2 @ a1 + b2) [256][16]; kb[s] = f @ dxdt ; 4 rows/thread
        {
            float4 acc = make_float4(0.f, 0.f, 0.f, 0.f);
            if constexpr (TR) {
                #pragma unroll 8
                for (int k = 0; k < W_; ++k) {
                    float4 wv = w24[k * (HXC / 4) + tid];
                    float av = a1s[k];
                    acc.x += wv.x * av; acc.y += wv.y * av;
                    acc.z += wv.z * av; acc.w += wv.w * av;
                }
            } else {
                const int jj = tid * 4;
                #pragma unroll 4
                for (int k = 0; k < W_; ++k) {
                    float av = a1s[k];
                    acc.x += w2[(jj + 0) * W_ + k] * av;
                    acc.y += w2[(jj + 1) * W_ + k] * av;
                    acc.z += w2[(jj + 2) * W_ + k] * av;
                    acc.w += w2[(jj + 3) * W_ + k] * av;
                }
            }
            const int c0 = (tid * 4) & 15;
            float p = tanhf(acc.x + bb.x) * dxs[c0]
                    + tanhf(acc.y + bb.y) * dxs[c0 + 1]
                    + tanhf(acc.z + bb.z) * dxs[c0 + 2]
                    + tanhf(acc.w + bb.w) * dxs[c0 + 3];
            p += __shfl_xor(p, 1);
            p += __shfl_xor(p, 2);
            if ((tid & 3) == 0) kb[s][tid >> 2] = p;
        }
        __syncthreads();
    };

    // ---------------- ODE: 99 intervals x 2 dopri5 substeps ----------------
    for (int i = 0; i < T_ - L_IN - 1; ++i) {
        float dt = tvals[L_IN + i + 1] - tvals[L_IN + i];
        if (tid < XC_) {
            float xa, xbv;
            if (tid < XC_ - 1) {
                xa  = cx[(b * T_ + L_IN + i) * (XC_ - 1) + tid];
                xbv = cx[(b * T_ + L_IN + i + 1) * (XC_ - 1) + tid];
            } else {
                xa  = tvals[L_IN + i];
                xbv = tvals[L_IN + i + 1];
            }
            dxs[tid] = (xbv - xa) / dt;
        }
        const float hh = dt * 0.5f;   // N_SUB = 2
        __syncthreads();

        for (int sub = 0; sub < 2; ++sub) {
            vf(z, 0);
            if (tid < H_) zs[tid] = z[tid] + hh * (0.2f * kb[0][tid]);
            __syncthreads();
            vf(zs, 1);
            if (tid < H_) zs[tid] = z[tid] + hh * (0.075f * kb[0][tid] + 0.225f * kb[1][tid]);
            __syncthreads();
            vf(zs, 2);
            if (tid < H_) zs[tid] = z[tid] + hh * ((44.f / 45.f) * kb[0][tid]
                                                - (56.f / 15.f) * kb[1][tid]
                                                + (32.f / 9.f) * kb[2][tid]);
            __syncthreads();
            vf(zs, 3);
            if (tid < H_) zs[tid] = z[tid] + hh * ((19372.f / 6561.f) * kb[0][tid]
                                                - (25360.f / 2187.f) * kb[1][tid]
                                                + (64448.f / 6561.f) * kb[2][tid]
                                                - (212.f / 729.f) * kb[3][tid]);
            __syncthreads();
            vf(zs, 4);
            if (tid < H_) zs[tid] = z[tid] + hh * ((9017.f / 3168.f) * kb[0][tid]
                                                - (355.f / 33.f) * kb[1][tid]
                                                + (46732.f / 5247.f) * kb[2][tid]
                                                + (49.f / 176.f) * kb[3][tid]
                                                - (5103.f / 18656.f) * kb[4][tid]);
            __syncthreads();
            vf(zs, 5);
            if (tid < H_) {
                z[tid] = z[tid] + hh * ((35.f / 384.f) * kb[0][tid]
                                      + (500.f / 1113.f) * kb[2][tid]
                                      + (125.f / 192.f) * kb[3][tid]
                                      - (2187.f / 6784.f) * kb[4][tid]
                                      + (11.f / 84.f) * kb[5][tid]);
            }
            __syncthreads();
        }
        readout(i + 1);
    }
}

extern "C" void kernel_launch(void* const* d_in, const int* in_sizes, int n_in,
                              void* d_out, int out_size, void* d_ws, size_t ws_size,
                              hipStream_t stream) {
    const float* y_past = (const float*)d_in[0];
    const float* tvals  = (const float*)d_in[1];
    const float* cx     = (const float*)d_in[2];
    const float* wih    = (const float*)d_in[3];
    const float* whh    = (const float*)d_in[4];
    const float* gb     = (const float*)d_in[5];
    const float* gbn    = (const float*)d_in[6];
    const float* w0     = (const float*)d_in[7];
    const float* b0     = (const float*)d_in[8];
    const float* w1     = (const float*)d_in[9];
    const float* b1     = (const float*)d_in[10];
    const float* w2     = (const float*)d_in[11];
    const float* b2     = (const float*)d_in[12];
    const float* ro_w   = (const float*)d_in[13];
    const float* ro_b   = (const float*)d_in[14];
    float* out = (float*)d_out;

    bool tr = ws_size >= WS_FLOATS * sizeof(float);
    if (tr) {
        float* ws = (float*)d_ws;
        auto launchT = [&](const float* in, float* o, int R, int K) {
            int n = R * K;
            transpose_kernel<<<(n + 255) / 256, 256, 0, stream>>>(in, o, R, K);
        };
        launchT(wih, ws + OFF_WIHT, GR_, S_ + XC_);
        launchT(whh, ws + OFF_WHHT, GR_, H_);
        launchT(w0,  ws + OFF_W0T,  W_, H_);
        launchT(w1,  ws + OFF_W1T,  W_, W_);
        launchT(w2,  ws + OFF_W2T,  HXC, W_);
        gru_cde_kernel<true><<<B_, NT, 0, stream>>>(
            y_past, tvals, cx,
            ws + OFF_WIHT, ws + OFF_WHHT, gb, gbn,
            ws + OFF_W0T, b0, ws + OFF_W1T, b1, ws + OFF_W2T, b2,
            ro_w, ro_b, out);
    } else {
        gru_cde_kernel<false><<<B_, NT, 0, stream>>>(
            y_past, tvals, cx,
            wih, whh, gb, gbn,
            w0, b0, w1, b1, w2, b2,
            ro_w, ro_b, out);
    }
}